// Round 9
// baseline (74.258 us; speedup 1.0000x reference)
//
#include <hip/hip_runtime.h>
#include <hip/hip_bf16.h>
#include <math.h>

#define NB   2048
#define NC   1000
#define DDIM 128
#define NPB  136      // compact triangular proto blocks (by<=bx<16)

typedef __attribute__((ext_vector_type(8))) short  short8;
typedef __attribute__((ext_vector_type(4))) float  floatx4;

// load 8 consecutive fp32, accumulate sum-of-squares, return packed bf16 (RNE)
__device__ __forceinline__ short8 ld_cvt8(const float* __restrict__ p, float& nrm) {
    float4 u = *(const float4*)p;
    float4 v = *(const float4*)(p + 4);
    nrm = fmaf(u.x, u.x, nrm); nrm = fmaf(u.y, u.y, nrm);
    nrm = fmaf(u.z, u.z, nrm); nrm = fmaf(u.w, u.w, nrm);
    nrm = fmaf(v.x, v.x, nrm); nrm = fmaf(v.y, v.y, nrm);
    nrm = fmaf(v.z, v.z, nrm); nrm = fmaf(v.w, v.w, nrm);
    union { short8 s; __hip_bfloat162 h[4]; } r;
    r.h[0] = __float22bfloat162_rn(make_float2(u.x, u.y));
    r.h[1] = __float22bfloat162_rn(make_float2(u.z, u.w));
    r.h[2] = __float22bfloat162_rn(make_float2(v.x, v.y));
    r.h[3] = __float22bfloat162_rn(make_float2(v.z, v.w));
    return r.s;
}

#define MFMA16(A, B, C) __builtin_amdgcn_mfma_f32_16x16x32_bf16(A, B, C, 0, 0, 0)

// ---- proto: compact upper-triangle 64x64 tiles, LDS-free fragments ---------------
__global__ __launch_bounds__(256) void proto_kernel(const float* __restrict__ W,
                                                    float* __restrict__ ws) {
    __shared__ float red[4];
    int bid = blockIdx.x;
    int by = 0, base = 0;                      // map bid -> (by<=bx<16)
    while (base + (16 - by) <= bid) { base += 16 - by; ++by; }
    int bx = by + (bid - base);
    int row0 = by * 64, col0 = bx * 64;
    int t = threadIdx.x;
    int lane = t & 63, w = t >> 6;
    int lm = lane & 15, q = lane >> 4;
    int wm = (w >> 1) * 32, wn = (w & 1) * 32;

    int ra0 = row0 + wm + lm;      if (ra0 > NC - 1) ra0 = NC - 1;
    int ra1 = row0 + wm + 16 + lm; if (ra1 > NC - 1) ra1 = NC - 1;
    int rb0 = col0 + wn + lm;      if (rb0 > NC - 1) rb0 = NC - 1;
    int rb1 = col0 + wn + 16 + lm; if (rb1 > NC - 1) rb1 = NC - 1;
    const float* pa0 = W + ra0 * DDIM;
    const float* pa1 = W + ra1 * DDIM;
    const float* pb0 = W + rb0 * DDIM;
    const float* pb1 = W + rb1 * DDIM;

    float na0 = 0, na1 = 0, nb0 = 0, nb1 = 0;
    floatx4 acc[2][2] = {{{0,0,0,0},{0,0,0,0}},{{0,0,0,0},{0,0,0,0}}};
    #pragma unroll
    for (int ks = 0; ks < 4; ++ks) {
        int ko = ks * 32 + q * 8;
        short8 a0 = ld_cvt8(pa0 + ko, na0);
        short8 a1 = ld_cvt8(pa1 + ko, na1);
        short8 b0 = ld_cvt8(pb0 + ko, nb0);
        short8 b1 = ld_cvt8(pb1 + ko, nb1);
        acc[0][0] = MFMA16(a0, b0, acc[0][0]);
        acc[0][1] = MFMA16(a0, b1, acc[0][1]);
        acc[1][0] = MFMA16(a1, b0, acc[1][0]);
        acc[1][1] = MFMA16(a1, b1, acc[1][1]);
    }
    na0 += __shfl_xor(na0, 16); na0 += __shfl_xor(na0, 32);
    na1 += __shfl_xor(na1, 16); na1 += __shfl_xor(na1, 32);
    nb0 += __shfl_xor(nb0, 16); nb0 += __shfl_xor(nb0, 32);
    nb1 += __shfl_xor(nb1, 16); nb1 += __shfl_xor(nb1, 32);

    float local = 0.0f;
    #pragma unroll
    for (int ci = 0; ci < 2; ++ci) {
        #pragma unroll
        for (int r = 0; r < 4; ++r) {
            int c1 = row0 + wm + ci * 16 + q * 4 + r;
            float n1 = __shfl(ci ? na1 : na0, q * 4 + r);
            if (c1 < NC) {
                #pragma unroll
                for (int bj = 0; bj < 2; ++bj) {
                    int c2 = col0 + wn + bj * 16 + lm;
                    if (c2 < NC) {
                        float d2 = n1 + (bj ? nb1 : nb0) - 2.0f * acc[ci][bj][r];
                        local += sqrtf(fmaxf(d2, 0.0f));
                    }
                }
            }
        }
    }
    if (by != bx) local *= 2.0f;               // symmetric double-count
    #pragma unroll
    for (int off = 32; off > 0; off >>= 1) local += __shfl_down(local, off);
    if (lane == 0) red[w] = local;
    __syncthreads();
    if (t == 0) ws[bid] = red[0] + red[1] + red[2] + red[3];
}

// ---- dist: 64x64 tiles, LDS-free, barrier-free; m=c (A<-W), n=b (B<-F) -----------
__global__ __launch_bounds__(256) void dist_kernel(const float* __restrict__ F,
                                                   const float* __restrict__ W,
                                                   const float* __restrict__ ws,
                                                   float* __restrict__ out) {
    int t = threadIdx.x;
    int lane = t & 63, w = t >> 6;
    int lm = lane & 15, q = lane >> 4;
    int row0 = blockIdx.y * 64, col0 = blockIdx.x * 64;   // row0: F rows, col0: W rows
    int wc = (w >> 1) * 32, wb = (w & 1) * 32;

    // proto scalar: per-wave redundant reduce of the 136 partials (no LDS/barrier)
    float pv = ws[lane] + ws[64 + lane] + (lane < 8 ? ws[128 + lane] : 0.0f);
    #pragma unroll
    for (int m = 1; m < 64; m <<= 1) pv += __shfl_xor(pv, m);
    float proto = pv;

    int ra0 = col0 + wc + lm;      if (ra0 > NC - 1) ra0 = NC - 1;
    int ra1 = col0 + wc + 16 + lm; if (ra1 > NC - 1) ra1 = NC - 1;
    int rb0 = row0 + wb + lm;                              // NB=2048: exact fit
    int rb1 = row0 + wb + 16 + lm;
    const float* pa0 = W + ra0 * DDIM;
    const float* pa1 = W + ra1 * DDIM;
    const float* pb0 = F + rb0 * DDIM;
    const float* pb1 = F + rb1 * DDIM;

    float na0 = 0, na1 = 0, nb0 = 0, nb1 = 0;
    floatx4 acc[2][2] = {{{0,0,0,0},{0,0,0,0}},{{0,0,0,0},{0,0,0,0}}};
    #pragma unroll
    for (int ks = 0; ks < 4; ++ks) {
        int ko = ks * 32 + q * 8;
        short8 a0 = ld_cvt8(pa0 + ko, na0);
        short8 a1 = ld_cvt8(pa1 + ko, na1);
        short8 b0 = ld_cvt8(pb0 + ko, nb0);
        short8 b1 = ld_cvt8(pb1 + ko, nb1);
        acc[0][0] = MFMA16(a0, b0, acc[0][0]);
        acc[0][1] = MFMA16(a0, b1, acc[0][1]);
        acc[1][0] = MFMA16(a1, b0, acc[1][0]);
        acc[1][1] = MFMA16(a1, b1, acc[1][1]);
    }
    na0 += __shfl_xor(na0, 16); na0 += __shfl_xor(na0, 32);
    na1 += __shfl_xor(na1, 16); na1 += __shfl_xor(na1, 32);
    nb0 += __shfl_xor(nb0, 16); nb0 += __shfl_xor(nb0, 32);
    nb1 += __shfl_xor(nb1, 16); nb1 += __shfl_xor(nb1, 32);

    #pragma unroll
    for (int ci = 0; ci < 2; ++ci) {
        int cb = col0 + wc + ci * 16 + q * 4;              // quad-aligned c base
        if (cb < NC) {                                     // NC%4==0: all-or-nothing
            float nw0 = __shfl(ci ? na1 : na0, q * 4 + 0);
            float nw1 = __shfl(ci ? na1 : na0, q * 4 + 1);
            float nw2 = __shfl(ci ? na1 : na0, q * 4 + 2);
            float nw3 = __shfl(ci ? na1 : na0, q * 4 + 3);
            #pragma unroll
            for (int bj = 0; bj < 2; ++bj) {
                int bg = row0 + wb + bj * 16 + lm;
                float nb_ = bj ? nb1 : nb0;
                floatx4 d = acc[ci][bj];
                float4 o;
                o.x = proto - sqrtf(fmaxf(nw0 + nb_ - 2.0f * d[0], 0.0f));
                o.y = proto - sqrtf(fmaxf(nw1 + nb_ - 2.0f * d[1], 0.0f));
                o.z = proto - sqrtf(fmaxf(nw2 + nb_ - 2.0f * d[2], 0.0f));
                o.w = proto - sqrtf(fmaxf(nw3 + nb_ - 2.0f * d[3], 0.0f));
                *(float4*)(out + bg * NC + cb) = o;
            }
        }
    }
}

extern "C" void kernel_launch(void* const* d_in, const int* in_sizes, int n_in,
                              void* d_out, int out_size, void* d_ws, size_t ws_size,
                              hipStream_t stream) {
    const float* F  = (const float*)d_in[0];   // (2048,128)
    const float* Wm = (const float*)d_in[1];   // (1000,128)
    float* out = (float*)d_out;                // (2048,1000)
    float* ws  = (float*)d_ws;

    proto_kernel<<<NPB, 256, 0, stream>>>(Wm, ws);                  // 136 partials
    dist_kernel <<<dim3(16, 32), 256, 0, stream>>>(F, Wm, ws, out); // 512 tiles
}

// Round 10
// 67.088 us; speedup vs baseline: 1.1069x; 1.1069x over previous
//
#include <hip/hip_runtime.h>
#include <hip/hip_bf16.h>
#include <math.h>

#define NB   2048
#define NC   1000
#define DDIM 128
#define LDT  136      // LDS row stride in bf16 (+8 pad; 272 B rows keep 16B align)
#define NPB  136      // compact triangular proto blocks (by<=bx<16)

typedef __attribute__((ext_vector_type(8))) short  short8;
typedef __attribute__((ext_vector_type(4))) float  floatx4;

__device__ __forceinline__ float bf2f(unsigned short b) {
    union { float f; unsigned int u; } v; v.u = ((unsigned int)b) << 16;
    return v.f;
}

// stage 64 rows x 128 k of fp32 -> bf16 LDS tile (RNE), coalesced float4 reads
__device__ __forceinline__ void stage_cvt(const float* __restrict__ src, int row0, int clampr,
                                          unsigned short* __restrict__ lds, int t) {
    #pragma unroll
    for (int i = 0; i < 8; ++i) {
        int c = (i * 256 + t) * 4;
        int r = c >> 7, k = c & 127;
        int gr = row0 + r; if (gr > clampr) gr = clampr;
        float4 v = *(const float4*)(src + gr * DDIM + k);
        union { __hip_bfloat162 h; unsigned int u; } p0, p1;
        p0.h = __float22bfloat162_rn(make_float2(v.x, v.y));
        p1.h = __float22bfloat162_rn(make_float2(v.z, v.w));
        uint2 st; st.x = p0.u; st.y = p1.u;
        *(uint2*)(lds + r * LDT + k) = st;
    }
}

// read fragment from LDS row, accumulate sum-of-squares of its 8 bf16 values
__device__ __forceinline__ short8 frag_n(const unsigned short* __restrict__ p, float& nrm) {
    short8 v = *(const short8*)p;
    #pragma unroll
    for (int e = 0; e < 8; ++e) { float f = bf2f((unsigned short)v[e]); nrm = fmaf(f, f, nrm); }
    return v;
}

#define MFMA16(A, B, C) __builtin_amdgcn_mfma_f32_16x16x32_bf16(A, B, C, 0, 0, 0)

// per-row squared norms (proto kernel only); 4 lanes per row
__device__ __forceinline__ void norm64(const unsigned short* __restrict__ tile,
                                       float* __restrict__ nrm, int t) {
    int r = t >> 2, seg = t & 3;
    const unsigned short* p = tile + r * LDT + seg * 32;
    float q = 0.0f;
    #pragma unroll
    for (int j = 0; j < 4; ++j) {
        short8 v = *(const short8*)(p + j * 8);
        #pragma unroll
        for (int e = 0; e < 8; ++e) { float f = bf2f((unsigned short)v[e]); q = fmaf(f, f, q); }
    }
    q += __shfl_xor(q, 1);
    q += __shfl_xor(q, 2);
    if (seg == 0) nrm[r] = q;
}

// ---- proto: compact upper-triangle 64x64 tiles, partial -> ws[bid] ---------------
__global__ __launch_bounds__(256) void proto_kernel(const float* __restrict__ W,
                                                    float* __restrict__ ws) {
    __shared__ __align__(16) unsigned short As[64 * LDT];
    __shared__ __align__(16) unsigned short Bs[64 * LDT];
    __shared__ float nA[64], nB[64], red[4];
    int bid = blockIdx.x;
    int by = 0, base = 0;                      // map bid -> (by<=bx<16)
    while (base + (16 - by) <= bid) { base += 16 - by; ++by; }
    int bx = by + (bid - base);
    int t = threadIdx.x;
    int row0 = by * 64, col0 = bx * 64;
    stage_cvt(W, row0, NC - 1, As, t);
    stage_cvt(W, col0, NC - 1, Bs, t);
    __syncthreads();
    norm64(As, nA, t);
    norm64(Bs, nB, t);
    int lane = t & 63, w = t >> 6;
    int wm = (w >> 1) * 32, wn = (w & 1) * 32;
    int lm = lane & 15, q = lane >> 4;
    floatx4 acc[2][2] = {{{0,0,0,0},{0,0,0,0}},{{0,0,0,0},{0,0,0,0}}};
    #pragma unroll
    for (int ks = 0; ks < 4; ++ks) {
        int ko = ks * 32 + q * 8;
        short8 a0 = *(const short8*)(As + (wm + lm) * LDT + ko);
        short8 a1 = *(const short8*)(As + (wm + 16 + lm) * LDT + ko);
        short8 b0 = *(const short8*)(Bs + (wn + lm) * LDT + ko);
        short8 b1 = *(const short8*)(Bs + (wn + 16 + lm) * LDT + ko);
        acc[0][0] = MFMA16(a0, b0, acc[0][0]);
        acc[0][1] = MFMA16(a0, b1, acc[0][1]);
        acc[1][0] = MFMA16(a1, b0, acc[1][0]);
        acc[1][1] = MFMA16(a1, b1, acc[1][1]);
    }
    __syncthreads();                           // norms visible
    float local = 0.0f;
    #pragma unroll
    for (int ti = 0; ti < 2; ++ti)
        #pragma unroll
        for (int tj = 0; tj < 2; ++tj) {
            int lc2 = wn + tj * 16 + lm;
            if (col0 + lc2 < NC) {
                float n2 = nB[lc2];
                #pragma unroll
                for (int r = 0; r < 4; ++r) {
                    int lc1 = wm + ti * 16 + q * 4 + r;
                    if (row0 + lc1 < NC) {
                        float d2 = nA[lc1] + n2 - 2.0f * acc[ti][tj][r];
                        local += sqrtf(fmaxf(d2, 0.0f));
                    }
                }
            }
        }
    if (by != bx) local *= 2.0f;               // symmetric double-count
    #pragma unroll
    for (int off = 32; off > 0; off >>= 1) local += __shfl_down(local, off);
    if (lane == 0) red[w] = local;
    __syncthreads();
    if (t == 0) ws[bid] = red[0] + red[1] + red[2] + red[3];
}

// ---- dist: 64x64 tiles, staged LDS, ONE barrier; m=c (A<-W), n=b (B<-F) ----------
__global__ __launch_bounds__(256) void dist_kernel(const float* __restrict__ F,
                                                   const float* __restrict__ W,
                                                   const float* __restrict__ ws,
                                                   float* __restrict__ out) {
    __shared__ __align__(16) unsigned short Fs[64 * LDT];
    __shared__ __align__(16) unsigned short Ws[64 * LDT];
    __shared__ float red2[4];
    int t = threadIdx.x;
    int row0 = blockIdx.y * 64, col0 = blockIdx.x * 64;   // row0: F rows, col0: W rows

    float pv = (t < NPB) ? ws[t] : 0.0f;       // proto partials (coalesced 544 B)
    stage_cvt(F, row0, NB - 1, Fs, t);
    stage_cvt(W, col0, NC - 1, Ws, t);
    #pragma unroll
    for (int off = 32; off > 0; off >>= 1) pv += __shfl_down(pv, off);
    if ((t & 63) == 0) red2[t >> 6] = pv;
    __syncthreads();                           // single barrier: staging + red2 visible
    float proto = red2[0] + red2[1] + red2[2] + red2[3];

    int lane = t & 63, w = t >> 6;
    int wc = (w >> 1) * 32, wb = (w & 1) * 32; // wave offsets: c (m-dim), b (n-dim)
    int lm = lane & 15, q = lane >> 4;
    // A-frag from W tile (m=c), B-frag from F tile (n=b):
    //   D col = lane&15 -> b_local, D row = q*4+reg -> c_local (4 consecutive c/lane)
    // Norms accumulated from the fragments themselves (rounded values), then
    // completed across the 4 q-quads via shfl_xor — no LDS, no second barrier.
    float na0 = 0, na1 = 0, nb0 = 0, nb1 = 0;
    floatx4 acc[2][2] = {{{0,0,0,0},{0,0,0,0}},{{0,0,0,0},{0,0,0,0}}};
    #pragma unroll
    for (int ks = 0; ks < 4; ++ks) {
        int ko = ks * 32 + q * 8;
        short8 a0 = frag_n(Ws + (wc + lm) * LDT + ko, na0);
        short8 a1 = frag_n(Ws + (wc + 16 + lm) * LDT + ko, na1);
        short8 b0 = frag_n(Fs + (wb + lm) * LDT + ko, nb0);
        short8 b1 = frag_n(Fs + (wb + 16 + lm) * LDT + ko, nb1);
        acc[0][0] = MFMA16(a0, b0, acc[0][0]);
        acc[0][1] = MFMA16(a0, b1, acc[0][1]);
        acc[1][0] = MFMA16(a1, b0, acc[1][0]);
        acc[1][1] = MFMA16(a1, b1, acc[1][1]);
    }
    na0 += __shfl_xor(na0, 16); na0 += __shfl_xor(na0, 32);  // W row wc+lm
    na1 += __shfl_xor(na1, 16); na1 += __shfl_xor(na1, 32);  // W row wc+16+lm
    nb0 += __shfl_xor(nb0, 16); nb0 += __shfl_xor(nb0, 32);  // F row wb+lm
    nb1 += __shfl_xor(nb1, 16); nb1 += __shfl_xor(nb1, 32);  // F row wb+16+lm

    #pragma unroll
    for (int ci = 0; ci < 2; ++ci) {
        int cb = col0 + wc + ci * 16 + q * 4;              // quad-aligned c base
        if (cb < NC) {                                     // NC%4==0: all-or-nothing
            float nw0 = __shfl(ci ? na1 : na0, q * 4 + 0); // held by lane lm'=q*4+r
            float nw1 = __shfl(ci ? na1 : na0, q * 4 + 1);
            float nw2 = __shfl(ci ? na1 : na0, q * 4 + 2);
            float nw3 = __shfl(ci ? na1 : na0, q * 4 + 3);
            #pragma unroll
            for (int bj = 0; bj < 2; ++bj) {
                int bg = row0 + wb + bj * 16 + lm;         // this lane's F row
                float nb_ = bj ? nb1 : nb0;
                floatx4 d = acc[ci][bj];
                float4 o;
                o.x = proto - sqrtf(fmaxf(nw0 + nb_ - 2.0f * d[0], 0.0f));
                o.y = proto - sqrtf(fmaxf(nw1 + nb_ - 2.0f * d[1], 0.0f));
                o.z = proto - sqrtf(fmaxf(nw2 + nb_ - 2.0f * d[2], 0.0f));
                o.w = proto - sqrtf(fmaxf(nw3 + nb_ - 2.0f * d[3], 0.0f));
                *(float4*)(out + bg * NC + cb) = o;
            }
        }
    }
}

extern "C" void kernel_launch(void* const* d_in, const int* in_sizes, int n_in,
                              void* d_out, int out_size, void* d_ws, size_t ws_size,
                              hipStream_t stream) {
    const float* F  = (const float*)d_in[0];   // (2048,128)
    const float* Wm = (const float*)d_in[1];   // (1000,128)
    float* out = (float*)d_out;                // (2048,1000)
    float* ws  = (float*)d_ws;

    proto_kernel<<<NPB, 256, 0, stream>>>(Wm, ws);                  // 136 partials
    dist_kernel <<<dim3(16, 32), 256, 0, stream>>>(F, Wm, ws, out); // 512 tiles
}